// Round 1
// baseline (3021.212 us; speedup 1.0000x reference)
//
#include <hip/hip_runtime.h>
#include <hip/hip_bf16.h>

// Problem constants
#define NB 8
#define NS 2048
#define ND 768
#define NH 8
#define NHD 96
// scale = 1/sqrt(96)
#define ATTN_SCALE 0.1020620726159658f

__device__ __forceinline__ float bf2f(unsigned short u) {
    union { unsigned int i; float f; } x;
    x.i = ((unsigned int)u) << 16;
    return x.f;
}

// ---------------------------------------------------------------------------
// Kernel 1: QKV projection.  C[M=16384, N=768] = X[M,768] @ W[N,768]^T + bias
// Output scattered to [B, H, S, HD] layout, stored bf16.
// blockIdx.z in {0,1,2} selects (Wq,bq,Q) / (Wk,bk,K) / (Wv,bv,V).
// 64x64 tile per block, 256 threads, 4x4 micro-tile.
// LDS stored k-major (transposed) with +4 pad so inner loop is ds_read_b128.
// ---------------------------------------------------------------------------
__global__ __launch_bounds__(256) void qkv_proj(
    const float* __restrict__ X,
    const float* __restrict__ Wq, const float* __restrict__ bq,
    const float* __restrict__ Wk, const float* __restrict__ bk,
    const float* __restrict__ Wv, const float* __restrict__ bv,
    __hip_bfloat16* __restrict__ Qo, __hip_bfloat16* __restrict__ Ko,
    __hip_bfloat16* __restrict__ Vo)
{
    const float* W; const float* bias; __hip_bfloat16* Out;
    if (blockIdx.z == 0)      { W = Wq; bias = bq; Out = Qo; }
    else if (blockIdx.z == 1) { W = Wk; bias = bk; Out = Ko; }
    else                      { W = Wv; bias = bv; Out = Vo; }

    __shared__ float As[64][68];  // As[k][m]
    __shared__ float Bs[64][68];  // Bs[k][n] = W[n][k]

    const int tid = threadIdx.x;
    const int ty = tid >> 4, tx = tid & 15;
    const int m0 = blockIdx.y << 6;
    const int n0 = blockIdx.x << 6;

    float acc[4][4] = {};

    for (int k0 = 0; k0 < ND; k0 += 64) {
        #pragma unroll
        for (int i = 0; i < 4; ++i) {
            const int f = tid + (i << 8);      // 0..1023 float4-chunks
            const int row = f >> 4;            // 0..63
            const int c4 = (f & 15) << 2;      // 0..60
            const float4 xv = *(const float4*)&X[(size_t)(m0 + row) * ND + k0 + c4];
            As[c4 + 0][row] = xv.x; As[c4 + 1][row] = xv.y;
            As[c4 + 2][row] = xv.z; As[c4 + 3][row] = xv.w;
            const float4 wv = *(const float4*)&W[(size_t)(n0 + row) * ND + k0 + c4];
            Bs[c4 + 0][row] = wv.x; Bs[c4 + 1][row] = wv.y;
            Bs[c4 + 2][row] = wv.z; Bs[c4 + 3][row] = wv.w;
        }
        __syncthreads();
        #pragma unroll 8
        for (int kk = 0; kk < 64; ++kk) {
            const float4 a = *(const float4*)&As[kk][ty << 2];
            const float4 b = *(const float4*)&Bs[kk][tx << 2];
            const float av[4] = {a.x, a.y, a.z, a.w};
            const float bv4[4] = {b.x, b.y, b.z, b.w};
            #pragma unroll
            for (int r = 0; r < 4; ++r)
                #pragma unroll
                for (int c = 0; c < 4; ++c)
                    acc[r][c] = fmaf(av[r], bv4[c], acc[r][c]);
        }
        __syncthreads();
    }

    #pragma unroll
    for (int r = 0; r < 4; ++r) {
        const int m = m0 + (ty << 2) + r;
        const int bb = m >> 11;            // m / S
        const int s = m & (NS - 1);        // m % S
        #pragma unroll
        for (int c = 0; c < 4; ++c) {
            const int n = n0 + (tx << 2) + c;
            const int h = n / NHD, hd = n % NHD;
            const float v = acc[r][c] + bias[n];
            Out[((size_t)(bb * NH + h) * NS + s) * NHD + hd] = __float2bfloat16(v);
        }
    }
}

// ---------------------------------------------------------------------------
// Kernel 2: flash-style masked attention + residual add.
// One block per (b, h, 64-row Q tile). 256 threads = 16x16.
// Each thread: 4x4 score micro-tile (rows ty*4.., cols tx*4..),
// O accumulator 4 rows x 6 hd-cols (cols tx*6..).
// Online softmax state (m, l) replicated across the 16 lanes of a row group.
// K tile and V tile share one LDS buffer (loads are separated by syncs).
// ---------------------------------------------------------------------------
__global__ __launch_bounds__(256) void attn(
    const __hip_bfloat16* __restrict__ Q, const __hip_bfloat16* __restrict__ K,
    const __hip_bfloat16* __restrict__ V, const int* __restrict__ adj,
    const float* __restrict__ features, float* __restrict__ out)
{
    __shared__ float Qs[NHD][64];   // Qs[d][qr]
    __shared__ float KVs[NHD][64];  // K phase: [d][kr]; V phase reused flat as [kr][d]
    __shared__ float Ps[64][64];    // P[qr][kr]

    const int tid = threadIdx.x;
    const int ty = tid >> 4, tx = tid & 15;
    const int qt = blockIdx.x, h = blockIdx.y, b = blockIdx.z;
    const int sq0 = qt << 6;

    const __hip_bfloat16* Qbase = Q + ((size_t)(b * NH + h) * NS + sq0) * NHD;
    const __hip_bfloat16* Kbase = K + (size_t)(b * NH + h) * NS * NHD;
    const __hip_bfloat16* Vbase = V + (size_t)(b * NH + h) * NS * NHD;
    const int* adjbase = adj + ((size_t)b * NS + sq0) * NS;

    // Load Q tile transposed: Qs[d][qr]
    #pragma unroll
    for (int i = 0; i < 6; ++i) {
        const int f = tid + (i << 8);     // 0..1535 ushort4-chunks
        const int row = f / 24;
        const int c4 = (f % 24) << 2;
        const ushort4 u = *(const ushort4*)&Qbase[row * NHD + c4];
        Qs[c4 + 0][row] = bf2f(u.x); Qs[c4 + 1][row] = bf2f(u.y);
        Qs[c4 + 2][row] = bf2f(u.z); Qs[c4 + 3][row] = bf2f(u.w);
    }

    float m_i[4], l_i[4], Oa[4][6];
    #pragma unroll
    for (int r = 0; r < 4; ++r) {
        m_i[r] = -INFINITY; l_i[r] = 0.f;
        #pragma unroll
        for (int c = 0; c < 6; ++c) Oa[r][c] = 0.f;
    }
    const int oc0 = tx * 6;

    for (int kt = 0; kt < 32; ++kt) {
        const int sk0 = kt << 6;

        // adjacency for this thread's 4x4 scores (issued early to hide latency)
        int4 adjv[4];
        #pragma unroll
        for (int r = 0; r < 4; ++r)
            adjv[r] = *(const int4*)&adjbase[((ty << 2) + r) * NS + sk0 + (tx << 2)];

        // Load K tile transposed: KVs[d][kr]
        #pragma unroll
        for (int i = 0; i < 6; ++i) {
            const int f = tid + (i << 8);
            const int row = f / 24;
            const int c4 = (f % 24) << 2;
            const ushort4 u = *(const ushort4*)&Kbase[(size_t)(sk0 + row) * NHD + c4];
            KVs[c4 + 0][row] = bf2f(u.x); KVs[c4 + 1][row] = bf2f(u.y);
            KVs[c4 + 2][row] = bf2f(u.z); KVs[c4 + 3][row] = bf2f(u.w);
        }
        __syncthreads();   // (a) K + Q visible

        // Scores: 4x4 per thread over d=0..95
        float sc[4][4] = {};
        #pragma unroll 8
        for (int d = 0; d < NHD; ++d) {
            const float4 a = *(const float4*)&Qs[d][ty << 2];
            const float4 kk = *(const float4*)&KVs[d][tx << 2];
            const float av[4] = {a.x, a.y, a.z, a.w};
            const float kv[4] = {kk.x, kk.y, kk.z, kk.w};
            #pragma unroll
            for (int r = 0; r < 4; ++r)
                #pragma unroll
                for (int c = 0; c < 4; ++c)
                    sc[r][c] = fmaf(av[r], kv[c], sc[r][c]);
        }
        __syncthreads();   // (b) done reading K from KVs

        // Mask + scale + online softmax update (registers + shuffles only)
        float p[4][4];
        #pragma unroll
        for (int r = 0; r < 4; ++r) {
            const int* am = (const int*)&adjv[r];
            #pragma unroll
            for (int c = 0; c < 4; ++c)
                sc[r][c] = am[c] ? sc[r][c] * ATTN_SCALE : -1e9f;
            float mt = fmaxf(fmaxf(sc[r][0], sc[r][1]), fmaxf(sc[r][2], sc[r][3]));
            mt = fmaxf(mt, __shfl_xor(mt, 1));
            mt = fmaxf(mt, __shfl_xor(mt, 2));
            mt = fmaxf(mt, __shfl_xor(mt, 4));
            mt = fmaxf(mt, __shfl_xor(mt, 8));
            const float mn = fmaxf(m_i[r], mt);
            const float alpha = __expf(m_i[r] - mn);  // exp(-inf)=0 on first tile
            float sum = 0.f;
            #pragma unroll
            for (int c = 0; c < 4; ++c) { p[r][c] = __expf(sc[r][c] - mn); sum += p[r][c]; }
            sum += __shfl_xor(sum, 1);
            sum += __shfl_xor(sum, 2);
            sum += __shfl_xor(sum, 4);
            sum += __shfl_xor(sum, 8);
            l_i[r] = l_i[r] * alpha + sum;
            m_i[r] = mn;
            #pragma unroll
            for (int c = 0; c < 6; ++c) Oa[r][c] *= alpha;
        }

        // Write P tile (prev-iter readers finished at sync (d))
        #pragma unroll
        for (int r = 0; r < 4; ++r)
            *(float4*)&Ps[(ty << 2) + r][tx << 2] =
                make_float4(p[r][0], p[r][1], p[r][2], p[r][3]);

        // Load V tile into same buffer, row-major: Vs[kr][d]
        float* Vs = &KVs[0][0];
        #pragma unroll
        for (int i = 0; i < 6; ++i) {
            const int f = tid + (i << 8);
            const int row = f / 24;
            const int c4 = (f % 24) << 2;
            const ushort4 u = *(const ushort4*)&Vbase[(size_t)(sk0 + row) * NHD + c4];
            Vs[row * NHD + c4 + 0] = bf2f(u.x); Vs[row * NHD + c4 + 1] = bf2f(u.y);
            Vs[row * NHD + c4 + 2] = bf2f(u.z); Vs[row * NHD + c4 + 3] = bf2f(u.w);
        }
        __syncthreads();   // (c) P + V visible

        // O += P @ V   (4 rows x 6 cols per thread)
        #pragma unroll 4
        for (int k = 0; k < 64; ++k) {
            float pv[4];
            #pragma unroll
            for (int r = 0; r < 4; ++r) pv[r] = Ps[(ty << 2) + r][k];  // broadcast
            const float2 v0 = *(const float2*)&Vs[k * NHD + oc0];
            const float2 v1 = *(const float2*)&Vs[k * NHD + oc0 + 2];
            const float2 v2 = *(const float2*)&Vs[k * NHD + oc0 + 4];
            const float vv[6] = {v0.x, v0.y, v1.x, v1.y, v2.x, v2.y};
            #pragma unroll
            for (int r = 0; r < 4; ++r)
                #pragma unroll
                for (int c = 0; c < 6; ++c)
                    Oa[r][c] = fmaf(pv[r], vv[c], Oa[r][c]);
        }
        __syncthreads();   // (d) done with P and V before next iter overwrites
    }

    // Epilogue: context/l + residual, scattered back to [B,S,D]
    #pragma unroll
    for (int r = 0; r < 4; ++r) {
        const int qr = (ty << 2) + r;
        const float inv = 1.0f / l_i[r];
        const size_t base = ((size_t)b * NS + sq0 + qr) * ND + h * NHD + oc0;
        #pragma unroll
        for (int c = 0; c < 6; ++c)
            out[base + c] = Oa[r][c] * inv + features[base + c];
    }
}

// ---------------------------------------------------------------------------
// Kernel 3: in-place LayerNorm over last dim (768). One wave per row.
// ---------------------------------------------------------------------------
__global__ __launch_bounds__(256) void ln_kernel(
    float* __restrict__ out, const float* __restrict__ gamma,
    const float* __restrict__ beta)
{
    const int row = (blockIdx.x << 2) + (threadIdx.x >> 6);
    const int lane = threadIdx.x & 63;
    float* p = out + (size_t)row * ND;

    float4 v[3];
    float s = 0.f, sq = 0.f;
    #pragma unroll
    for (int i = 0; i < 3; ++i) {
        v[i] = *(const float4*)&p[(i << 8) + (lane << 2)];
        s += v[i].x + v[i].y + v[i].z + v[i].w;
        sq += v[i].x * v[i].x + v[i].y * v[i].y + v[i].z * v[i].z + v[i].w * v[i].w;
    }
    #pragma unroll
    for (int off = 32; off; off >>= 1) {
        s += __shfl_xor(s, off);
        sq += __shfl_xor(sq, off);
    }
    const float mu = s * (1.0f / ND);
    const float var = sq * (1.0f / ND) - mu * mu;
    const float rs = rsqrtf(var + 1e-5f);
    #pragma unroll
    for (int i = 0; i < 3; ++i) {
        const int d = (i << 8) + (lane << 2);
        const float4 g = *(const float4*)&gamma[d];
        const float4 be = *(const float4*)&beta[d];
        float4 o;
        o.x = (v[i].x - mu) * rs * g.x + be.x;
        o.y = (v[i].y - mu) * rs * g.y + be.y;
        o.z = (v[i].z - mu) * rs * g.z + be.z;
        o.w = (v[i].w - mu) * rs * g.w + be.w;
        *(float4*)&p[d] = o;
    }
}

// ---------------------------------------------------------------------------
extern "C" void kernel_launch(void* const* d_in, const int* in_sizes, int n_in,
                              void* d_out, int out_size, void* d_ws, size_t ws_size,
                              hipStream_t stream) {
    (void)in_sizes; (void)n_in; (void)out_size; (void)ws_size;

    const float* features = (const float*)d_in[0];
    const int*   adj      = (const int*)d_in[1];
    const float* Wq       = (const float*)d_in[2];
    const float* bq       = (const float*)d_in[3];
    const float* Wk       = (const float*)d_in[4];
    const float* bk       = (const float*)d_in[5];
    const float* Wv       = (const float*)d_in[6];
    const float* bv       = (const float*)d_in[7];
    const float* gamma    = (const float*)d_in[8];
    const float* beta     = (const float*)d_in[9];
    float* out = (float*)d_out;

    const size_t elems = (size_t)NB * NS * ND;  // 12,582,912
    __hip_bfloat16* Qb = (__hip_bfloat16*)d_ws;
    __hip_bfloat16* Kb = Qb + elems;
    __hip_bfloat16* Vb = Kb + elems;

    // 1) QKV projections: grid (N/64, M/64, 3)
    dim3 g1(ND / 64, (NB * NS) / 64, 3);
    qkv_proj<<<g1, 256, 0, stream>>>(features, Wq, bq, Wk, bk, Wv, bv, Qb, Kb, Vb);

    // 2) Attention + residual: grid (S/64, H, B)
    dim3 g2(NS / 64, NH, NB);
    attn<<<g2, 256, 0, stream>>>(Qb, Kb, Vb, adj, features, out);

    // 3) LayerNorm in place: 4 rows per 256-thread block
    ln_kernel<<<(NB * NS) / 4, 256, 0, stream>>>(out, gamma, beta);
}

// Round 2
// 886.156 us; speedup vs baseline: 3.4093x; 3.4093x over previous
//
#include <hip/hip_runtime.h>
#include <hip/hip_bf16.h>

// Problem constants
#define NB 8
#define NS 2048
#define ND 768
#define NH 8
#define NHD 96
#define ATTN_SCALE 0.1020620726159658f   // 1/sqrt(96)

typedef short sh8 __attribute__((ext_vector_type(8)));   // 8 bf16 = 4 VGPRs (MFMA A/B frag)
typedef float f4  __attribute__((ext_vector_type(4)));   // MFMA C/D frag

__device__ __forceinline__ unsigned int pack_bf2(float a, float b) {
    __hip_bfloat162 h = __float22bfloat162_rn(make_float2(a, b));
    return *reinterpret_cast<unsigned int*>(&h);
}

// ---------------------------------------------------------------------------
// Kernel 1: QKV projection via bf16 MFMA.
//   Y[M=16384, N=768] = X[M,768] @ W[N,768]^T + b
// blockIdx.z: 0=Q (scaled by 1/sqrt(HD), layout [B,H,S,HD]),
//             1=K (layout [B,H,S,HD]), 2=V (layout [B,H,HD,S] -- transposed).
// 64x64 tile, 256 threads = 4 waves; wave w computes rows w*16..w*16+15.
// ---------------------------------------------------------------------------
__global__ __launch_bounds__(256) void qkv_mfma(
    const float* __restrict__ X,
    const float* __restrict__ Wq, const float* __restrict__ bq,
    const float* __restrict__ Wk, const float* __restrict__ bk,
    const float* __restrict__ Wv, const float* __restrict__ bv,
    __hip_bfloat16* __restrict__ Qo, __hip_bfloat16* __restrict__ Ko,
    __hip_bfloat16* __restrict__ Vo)
{
    const float* W; const float* bias; __hip_bfloat16* Out;
    const int z = blockIdx.z;
    if (z == 0)      { W = Wq; bias = bq; Out = Qo; }
    else if (z == 1) { W = Wk; bias = bk; Out = Ko; }
    else             { W = Wv; bias = bv; Out = Vo; }

    __shared__ unsigned short Xs[64][72];  // [m][k] bf16, pad->row stride 144B (16B-mult)
    __shared__ unsigned short Ws[64][72];  // [n][k] bf16

    const int tid  = threadIdx.x;
    const int w    = tid >> 6;
    const int lane = tid & 63;
    const int quad = lane >> 4;
    const int nl   = lane & 15;
    const int m0 = blockIdx.y << 6;
    const int n0 = blockIdx.x << 6;

    const f4 zero4 = {0.f, 0.f, 0.f, 0.f};
    f4 acc[4];
    #pragma unroll
    for (int i = 0; i < 4; ++i) acc[i] = zero4;

    for (int k0 = 0; k0 < ND; k0 += 64) {
        // Stage X and W tiles, converting fp32 -> bf16.
        #pragma unroll
        for (int i = 0; i < 4; ++i) {
            const int f = tid + (i << 8);       // 1024 float4-chunks
            const int row = f >> 4;
            const int c4 = (f & 15) << 2;
            const float4 xv = *(const float4*)&X[(size_t)(m0 + row) * ND + k0 + c4];
            *(uint2*)&Xs[row][c4] = make_uint2(pack_bf2(xv.x, xv.y), pack_bf2(xv.z, xv.w));
            const float4 wv = *(const float4*)&W[(size_t)(n0 + row) * ND + k0 + c4];
            *(uint2*)&Ws[row][c4] = make_uint2(pack_bf2(wv.x, wv.y), pack_bf2(wv.z, wv.w));
        }
        __syncthreads();

        // A-frags: lane holds X[w*16+nl][k0 + quad*8 + j]
        const sh8 a0 = *(const sh8*)&Xs[(w << 4) + nl][(quad << 3)];
        const sh8 a1 = *(const sh8*)&Xs[(w << 4) + nl][32 + (quad << 3)];
        #pragma unroll
        for (int ct = 0; ct < 4; ++ct) {
            const sh8 b0 = *(const sh8*)&Ws[(ct << 4) + nl][(quad << 3)];
            const sh8 b1 = *(const sh8*)&Ws[(ct << 4) + nl][32 + (quad << 3)];
            acc[ct] = __builtin_amdgcn_mfma_f32_16x16x32_bf16(a0, b0, acc[ct], 0, 0, 0);
            acc[ct] = __builtin_amdgcn_mfma_f32_16x16x32_bf16(a1, b1, acc[ct], 0, 0, 0);
        }
        __syncthreads();
    }

    // Epilogue: C layout row = quad*4+r, col = nl (within ct tile).
    const int mbase = m0 + (w << 4) + (quad << 2);
    #pragma unroll
    for (int ct = 0; ct < 4; ++ct) {
        const int n = n0 + (ct << 4) + nl;
        const int h = n / NHD, hd = n % NHD;
        const float bv_ = bias[n];
        #pragma unroll
        for (int r = 0; r < 4; ++r) {
            const int m = mbase + r;
            const int bb = m >> 11;         // m / NS
            const int s  = m & (NS - 1);
            float v = acc[ct][r] + bv_;
            if (z == 0) v *= ATTN_SCALE;
            size_t idx;
            if (z == 2) idx = ((size_t)(bb * NH + h) * NHD + hd) * NS + s;   // V^T
            else        idx = ((size_t)(bb * NH + h) * NS + s) * NHD + hd;
            Out[idx] = __float2bfloat16(v);
        }
    }
}

// ---------------------------------------------------------------------------
// Kernel 2: MFMA flash attention + residual.
// Block = (b, h, 64-row q-tile), 256 threads = 4 waves; wave w owns q rows
// w*16..w*16+15. Q frags in registers (pre-scaled). Per 64-kv tile:
// stage K [64][104] and V^T [96][72] in LDS; scores via MFMA; online softmax
// in C-layout registers; P through XOR-swizzled fp32 LDS -> bf16 A-frags; PV
// via MFMA.
// ---------------------------------------------------------------------------
__global__ __launch_bounds__(256) void attn_mfma(
    const __hip_bfloat16* __restrict__ Qg, const __hip_bfloat16* __restrict__ Kg,
    const __hip_bfloat16* __restrict__ Vtg, const int* __restrict__ adj,
    const float* __restrict__ features, float* __restrict__ out)
{
    __shared__ unsigned short Ks[64][104];  // [kv][d], row stride 208B (16B-mult)
    __shared__ unsigned short Vs[96][72];   // [d][kv], row stride 144B
    __shared__ float Ps[64][64];            // fp32, XOR-swizzled 4-dword groups

    const int tid  = threadIdx.x;
    const int w    = tid >> 6;
    const int lane = tid & 63;
    const int quad = lane >> 4;
    const int nl   = lane & 15;
    const int qt = blockIdx.x, h = blockIdx.y, b = blockIdx.z;
    const int sq0 = qt << 6;

    const size_t bh = (size_t)b * NH + h;
    const __hip_bfloat16* Qbase = Qg + (bh * NS + sq0) * NHD;
    const __hip_bfloat16* Kbase = Kg + bh * NS * NHD;
    const __hip_bfloat16* Vbase = Vtg + bh * NHD * NS;    // V^T: [hd][s]
    const int* adjbase = adj + ((size_t)b * NS + sq0) * NS;

    // Q fragments (A-operand): lane holds Q[w*16+nl][kc*32 + quad*8 + j]
    sh8 qf[3];
    #pragma unroll
    for (int kc = 0; kc < 3; ++kc)
        qf[kc] = *(const sh8*)&Qbase[(size_t)((w << 4) + nl) * NHD + kc * 32 + (quad << 3)];

    float m_i[4], l_i[4];
    f4 o[6];
    const f4 zero4 = {0.f, 0.f, 0.f, 0.f};
    #pragma unroll
    for (int t = 0; t < 6; ++t) o[t] = zero4;
    #pragma unroll
    for (int r = 0; r < 4; ++r) { m_i[r] = -INFINITY; l_i[r] = 0.f; }

    for (int kt = 0; kt < 32; ++kt) {
        const int sk0 = kt << 6;

        // ---- Stage K tile: 64 rows x 96 d = 768 16B-chunks ----
        #pragma unroll
        for (int i = 0; i < 3; ++i) {
            const int f = tid + (i << 8);
            const int row = f / 12, c8 = f % 12;
            *(uint4*)&Ks[row][c8 << 3] =
                *(const uint4*)&Kbase[(size_t)(sk0 + row) * NHD + (c8 << 3)];
        }
        // ---- Stage V^T tile: 96 rows x 64 kv = 768 16B-chunks ----
        #pragma unroll
        for (int i = 0; i < 3; ++i) {
            const int f = tid + (i << 8);
            const int row = f >> 3, c8 = f & 7;
            *(uint4*)&Vs[row][c8 << 3] =
                *(const uint4*)&Vbase[(size_t)row * NS + sk0 + (c8 << 3)];
        }
        __syncthreads();   // (a) K,V visible

        // ---- Scores: 16 q-rows x 64 kv per wave ----
        f4 sc[4];
        #pragma unroll
        for (int ct = 0; ct < 4; ++ct) sc[ct] = zero4;
        #pragma unroll
        for (int ct = 0; ct < 4; ++ct) {
            #pragma unroll
            for (int kc = 0; kc < 3; ++kc) {
                const sh8 kf = *(const sh8*)&Ks[(ct << 4) + nl][kc * 32 + (quad << 3)];
                sc[ct] = __builtin_amdgcn_mfma_f32_16x16x32_bf16(qf[kc], kf, sc[ct], 0, 0, 0);
            }
        }

        // ---- Adjacency mask (C layout: row = quad*4+r, col = ct*16+nl) ----
        int am[4][4];
        #pragma unroll
        for (int ct = 0; ct < 4; ++ct)
            #pragma unroll
            for (int r = 0; r < 4; ++r)
                am[ct][r] = adjbase[(size_t)((w << 4) + (quad << 2) + r) * NS +
                                    sk0 + (ct << 4) + nl];

        // ---- Online softmax (Q pre-scaled, so sc is already scaled) ----
        float pr[4][4];
        float alpha[4];
        #pragma unroll
        for (int r = 0; r < 4; ++r) {
            float s0 = am[0][r] ? sc[0][r] : -1e9f;
            float s1 = am[1][r] ? sc[1][r] : -1e9f;
            float s2 = am[2][r] ? sc[2][r] : -1e9f;
            float s3 = am[3][r] ? sc[3][r] : -1e9f;
            float mt = fmaxf(fmaxf(s0, s1), fmaxf(s2, s3));
            mt = fmaxf(mt, __shfl_xor(mt, 1));
            mt = fmaxf(mt, __shfl_xor(mt, 2));
            mt = fmaxf(mt, __shfl_xor(mt, 4));
            mt = fmaxf(mt, __shfl_xor(mt, 8));
            const float mn = fmaxf(m_i[r], mt);
            alpha[r] = __expf(m_i[r] - mn);
            m_i[r] = mn;
            const float p0 = __expf(s0 - mn);
            const float p1 = __expf(s1 - mn);
            const float p2 = __expf(s2 - mn);
            const float p3 = __expf(s3 - mn);
            pr[0][r] = p0; pr[1][r] = p1; pr[2][r] = p2; pr[3][r] = p3;
            float sum = p0 + p1 + p2 + p3;
            sum += __shfl_xor(sum, 1);
            sum += __shfl_xor(sum, 2);
            sum += __shfl_xor(sum, 4);
            sum += __shfl_xor(sum, 8);
            l_i[r] = l_i[r] * alpha[r] + sum;
        }
        #pragma unroll
        for (int t = 0; t < 6; ++t)
            #pragma unroll
            for (int r = 0; r < 4; ++r)
                o[t][r] *= alpha[r];

        // ---- Write P, XOR-swizzled: P[row][col] at Ps[row][((g^ (row&15))<<2)|o]
        const int rowbase = (w << 4) + (quad << 2);
        #pragma unroll
        for (int ct = 0; ct < 4; ++ct) {
            const int g = (ct << 2) + (nl >> 2);
            const int off = nl & 3;
            #pragma unroll
            for (int r = 0; r < 4; ++r) {
                const int rm = (quad << 2) + r;
                Ps[rowbase + r][((g ^ rm) << 2) | off] = pr[ct][r];
            }
        }
        __syncthreads();   // (b) P visible (cross-lane)

        // ---- P fragments: lane nl reads its row, 8 floats per k-chunk ----
        sh8 pf[2];
        #pragma unroll
        for (int kc2 = 0; kc2 < 2; ++kc2) {
            const int g0 = (kc2 << 3) + (quad << 1);   // even group of k-chunk start
            const f4 lo = *(const f4*)&Ps[(w << 4) + nl][((g0 ^ nl) << 2)];
            const f4 hi = *(const f4*)&Ps[(w << 4) + nl][(((g0 + 1) ^ nl) << 2)];
            union { uint4 u; sh8 s; } pu;
            pu.u = make_uint4(pack_bf2(lo[0], lo[1]), pack_bf2(lo[2], lo[3]),
                              pack_bf2(hi[0], hi[1]), pack_bf2(hi[2], hi[3]));
            pf[kc2] = pu.s;
        }

        // ---- PV: O[16 q][96 hd] += P[16][64] @ V[64][96] ----
        #pragma unroll
        for (int t = 0; t < 6; ++t) {
            #pragma unroll
            for (int kc2 = 0; kc2 < 2; ++kc2) {
                const sh8 vf = *(const sh8*)&Vs[(t << 4) + nl][(kc2 << 5) + (quad << 3)];
                o[t] = __builtin_amdgcn_mfma_f32_16x16x32_bf16(pf[kc2], vf, o[t], 0, 0, 0);
            }
        }
        __syncthreads();   // (c) done with Ks/Vs/Ps before next stage
    }

    // ---- Epilogue: O/l + residual ----
    #pragma unroll
    for (int r = 0; r < 4; ++r) {
        const int srow = sq0 + (w << 4) + (quad << 2) + r;
        const float inv = 1.0f / l_i[r];
        const size_t base = ((size_t)b * NS + srow) * ND + h * NHD;
        #pragma unroll
        for (int t = 0; t < 6; ++t) {
            const int d = (t << 4) + nl;
            out[base + d] = o[t][r] * inv + features[base + d];
        }
    }
}

// ---------------------------------------------------------------------------
// Kernel 3: in-place LayerNorm over last dim (768). One wave per row.
// ---------------------------------------------------------------------------
__global__ __launch_bounds__(256) void ln_kernel(
    float* __restrict__ out, const float* __restrict__ gamma,
    const float* __restrict__ beta)
{
    const int row = (blockIdx.x << 2) + (threadIdx.x >> 6);
    const int lane = threadIdx.x & 63;
    float* p = out + (size_t)row * ND;

    float4 v[3];
    float s = 0.f, sq = 0.f;
    #pragma unroll
    for (int i = 0; i < 3; ++i) {
        v[i] = *(const float4*)&p[(i << 8) + (lane << 2)];
        s += v[i].x + v[i].y + v[i].z + v[i].w;
        sq += v[i].x * v[i].x + v[i].y * v[i].y + v[i].z * v[i].z + v[i].w * v[i].w;
    }
    #pragma unroll
    for (int off = 32; off; off >>= 1) {
        s += __shfl_xor(s, off);
        sq += __shfl_xor(sq, off);
    }
    const float mu = s * (1.0f / ND);
    const float var = sq * (1.0f / ND) - mu * mu;
    const float rs = rsqrtf(var + 1e-5f);
    #pragma unroll
    for (int i = 0; i < 3; ++i) {
        const int d = (i << 8) + (lane << 2);
        const float4 g = *(const float4*)&gamma[d];
        const float4 be = *(const float4*)&beta[d];
        float4 ov;
        ov.x = (v[i].x - mu) * rs * g.x + be.x;
        ov.y = (v[i].y - mu) * rs * g.y + be.y;
        ov.z = (v[i].z - mu) * rs * g.z + be.z;
        ov.w = (v[i].w - mu) * rs * g.w + be.w;
        *(float4*)&p[d] = ov;
    }
}

// ---------------------------------------------------------------------------
extern "C" void kernel_launch(void* const* d_in, const int* in_sizes, int n_in,
                              void* d_out, int out_size, void* d_ws, size_t ws_size,
                              hipStream_t stream) {
    (void)in_sizes; (void)n_in; (void)out_size; (void)ws_size;

    const float* features = (const float*)d_in[0];
    const int*   adj      = (const int*)d_in[1];
    const float* Wq       = (const float*)d_in[2];
    const float* bq       = (const float*)d_in[3];
    const float* Wk       = (const float*)d_in[4];
    const float* bk       = (const float*)d_in[5];
    const float* Wv       = (const float*)d_in[6];
    const float* bv       = (const float*)d_in[7];
    const float* gamma    = (const float*)d_in[8];
    const float* beta     = (const float*)d_in[9];
    float* out = (float*)d_out;

    const size_t elems = (size_t)NB * NS * ND;  // 12,582,912
    __hip_bfloat16* Qb = (__hip_bfloat16*)d_ws;
    __hip_bfloat16* Kb = Qb + elems;
    __hip_bfloat16* Vb = Kb + elems;            // stored transposed [B,H,HD,S]

    // 1) QKV projections (MFMA): grid (N/64, M/64, 3)
    dim3 g1(ND / 64, (NB * NS) / 64, 3);
    qkv_mfma<<<g1, 256, 0, stream>>>(features, Wq, bq, Wk, bk, Wv, bv, Qb, Kb, Vb);

    // 2) MFMA flash attention + residual: grid (S/64, H, B)
    dim3 g2(NS / 64, NH, NB);
    attn_mfma<<<g2, 256, 0, stream>>>(Qb, Kb, Vb, adj, features, out);

    // 3) LayerNorm in place: 4 rows per 256-thread block
    ln_kernel<<<(NB * NS) / 4, 256, 0, stream>>>(out, gamma, beta);
}